// Round 8
// baseline (241.048 us; speedup 1.0000x reference)
//
#include <hip/hip_runtime.h>

// Problem constants: B=4, S=2048, D=1024
#define BB 4
#define SS 2048
#define DD 1024
#define MM 8192               // total rows
#define CH 64                 // scan chunks per batch
#define RR 32                 // rows per chunk (CH*RR = SS)
#define PI_F 3.14159265358979323846f

typedef __attribute__((ext_vector_type(8))) short bf16x8;
typedef __attribute__((ext_vector_type(4))) float f32x4;

// compiler-only scheduling fence: per-wave DS ops are processed in order by
// the LDS unit, so wave-local write->read needs no s_barrier, only a fence
// that stops the compiler from reordering the aliasing LDS accesses.
#define DSFENCE asm volatile("" ::: "memory")

// ---------------------------------------------------------------------------
// fp32 <-> bf16 helpers (RNE)
// ---------------------------------------------------------------------------
__device__ __forceinline__ unsigned short f2bf(float f) {
  unsigned int u = __float_as_uint(f);
  u = (u + 0x7FFFu + ((u >> 16) & 1u)) >> 16;
  return (unsigned short)u;
}
__device__ __forceinline__ float bf2f(unsigned short h) {
  return __uint_as_float(((unsigned int)h) << 16);
}

// one launch converts x (nx blocks) and, if grid is larger, the 3 W matrices
__global__ __launch_bounds__(256) void convert_all(
    const float* __restrict__ xs, const float* __restrict__ Wq,
    const float* __restrict__ Wk, const float* __restrict__ Wv,
    unsigned short* __restrict__ xb, unsigned short* __restrict__ Wb, int nx) {
  const int b = blockIdx.x;
  const float* src;
  unsigned short* dst;
  long off;
  if (b < nx) {
    src = xs; dst = xb; off = (long)b * 1024;
  } else {
    const int wb = b - nx;
    const int z = wb >> 10;
    src = (z == 0) ? Wq : (z == 1) ? Wk : Wv;
    dst = Wb + (size_t)z * DD * DD;
    off = (long)(wb & 1023) * 1024;
  }
  const long i = off + (long)threadIdx.x * 4;
  const float4 v = *(const float4*)&src[i];
  ushort4 o;
  o.x = f2bf(v.x); o.y = f2bf(v.y); o.z = f2bf(v.z); o.w = f2bf(v.w);
  *(ushort4*)&dst[i] = o;
}

// ---------------------------------------------------------------------------
// MFMA GEMM, BK=64 + XOR swizzle (R7 known-good: 0 bank conflicts).
// z=0: q fp32 -> outq. z=1,2: k,v bf16 -> KV ELEMENT-interleaved:
// row m, element n: k at ushort index m*2048 + 2n, v at m*2048 + 2n+1
// (so bind can load (k_n, v_n) as one coalesced 4B uint).
// ---------------------------------------------------------------------------
__device__ __forceinline__ void async16(const void* g, void* l) {
  __builtin_amdgcn_global_load_lds(
      (const __attribute__((address_space(1))) void*)g,
      (__attribute__((address_space(3))) void*)l, 16, 0, 0);
}

__global__ __launch_bounds__(256) void gemm_mfma(
    const unsigned short* __restrict__ xb,
    const unsigned short* __restrict__ Wb,
    float* __restrict__ outq, unsigned short* __restrict__ KV) {
  const int z = blockIdx.z;
  const unsigned short* W = Wb + (size_t)z * DD * DD;

  __shared__ unsigned short Als[128 * 64];
  __shared__ unsigned short Bls[128 * 64];

  const int tid  = threadIdx.x;
  const int lane = tid & 63;
  const int wave = tid >> 6;
  const int wm = (wave & 1) * 64;
  const int wn = (wave >> 1) * 64;

  const long m0 = (long)blockIdx.x * 128;
  const long n0 = (long)blockIdx.y * 128;

  f32x4 acc[4][4] = {};

  for (int k0 = 0; k0 < DD; k0 += 64) {
    #pragma unroll
    for (int i = 0; i < 4; ++i) {
      const int slot = i * 256 + tid;
      const int row  = slot >> 3;
      const int kq   = slot & 7;
      const int g    = kq ^ (row & 7);
      async16(xb + (m0 + row) * DD + k0 + g * 8, &Als[slot * 8]);
      async16(W  + (n0 + row) * DD + k0 + g * 8, &Bls[slot * 8]);
    }
    __syncthreads();

    const int fr = lane & 15;
    const int kq = lane >> 4;
    #pragma unroll
    for (int h = 0; h < 2; ++h) {
      bf16x8 af[4], bfr[4];
      #pragma unroll
      for (int mt = 0; mt < 4; ++mt) {
        const int row = wm + mt * 16 + fr;
        af[mt] = *(const bf16x8*)
            &Als[row * 64 + ((((h << 2) + kq) ^ (fr & 7)) << 3)];
      }
      #pragma unroll
      for (int nt = 0; nt < 4; ++nt) {
        const int row = wn + nt * 16 + fr;
        bfr[nt] = *(const bf16x8*)
            &Bls[row * 64 + ((((h << 2) + kq) ^ (fr & 7)) << 3)];
      }
      #pragma unroll
      for (int mt = 0; mt < 4; ++mt)
        #pragma unroll
        for (int nt = 0; nt < 4; ++nt)
          acc[mt][nt] = __builtin_amdgcn_mfma_f32_16x16x32_bf16(
              af[mt], bfr[nt], acc[mt][nt], 0, 0, 0);
    }
    __syncthreads();
  }

  const int col = lane & 15;
  const int r0  = (lane >> 4) * 4;
  if (z == 0) {
    #pragma unroll
    for (int mt = 0; mt < 4; ++mt)
      #pragma unroll
      for (int nt = 0; nt < 4; ++nt)
        #pragma unroll
        for (int r = 0; r < 4; ++r) {
          const long m = m0 + wm + mt * 16 + r0 + r;
          const long n = n0 + wn + nt * 16 + col;
          outq[m * DD + n] = acc[mt][nt][r];
        }
  } else {
    unsigned short* Ck = KV + (z - 1);     // interleave: k even, v odd
    #pragma unroll
    for (int mt = 0; mt < 4; ++mt)
      #pragma unroll
      for (int nt = 0; nt < 4; ++nt)
        #pragma unroll
        for (int r = 0; r < 4; ++r) {
          const long m = m0 + wm + mt * 16 + r0 + r;
          const long n = n0 + wn + nt * 16 + col;
          Ck[m * 2048 + 2 * n] = f2bf(acc[mt][nt][r]);
        }
  }
}

// ---------------------------------------------------------------------------
// Wave-local radix-4 FFT, N=1024: ONE 64-lane wave per transform, 4 virtual
// threads per lane (vthread t = lane + 64j), 16 float2 in registers.
// Identical stage math to R5-R7 (proven); exchanges become:
//   256->64 : pure in-register transpose x[j][n] <-> x[n][j]  (derived: the
//             generic write t+256n / read 256j+l+64n mapping stays in-lane)
//   others  : wave-private LDS, NO barriers (per-wave DS ordering + DSFENCE)
// ---------------------------------------------------------------------------
__device__ __forceinline__ int pidx(int i) { return i + (i >> 6); }
#define BUFSZ 1040

__device__ __forceinline__ int rev4(int p) {
  unsigned r = __brev((unsigned)p) >> 22;
  return (int)(((r & 0x155u) << 1) | ((r & 0x2AAu) >> 1));
}

__host__ __device__ constexpr int clog2(int s) {
  return (s == 256) ? 8 : (s == 64) ? 6 : (s == 16) ? 4 : (s == 4) ? 2 : 0;
}

template <int S>
__device__ __forceinline__ void fwd_stage(float2 x[4], int t) {
  float c1 = 1.0f, s1 = 0.0f;
  if (S > 1) {
    const int j = t & (S - 1);
    __sincosf(-2.0f * PI_F * (float)j / (float)(4 * S), &s1, &c1);
  }
  const float c2 = c1 * c1 - s1 * s1, s2 = 2.0f * c1 * s1;
  const float c3 = c1 * c2 - s1 * s2, s3 = c1 * s2 + s1 * c2;
  const float Ar = x[0].x + x[2].x, Ai = x[0].y + x[2].y;
  const float Br = x[1].x + x[3].x, Bi = x[1].y + x[3].y;
  const float Cr = x[0].x - x[2].x, Ci = x[0].y - x[2].y;
  const float dr = x[1].x - x[3].x, di = x[1].y - x[3].y;
  const float y1r = Cr + di, y1i = Ci - dr;
  const float y2r = Ar - Br, y2i = Ai - Bi;
  const float y3r = Cr - di, y3i = Ci + dr;
  x[0] = make_float2(Ar + Br, Ai + Bi);
  x[1] = make_float2(y1r * c1 - y1i * s1, y1r * s1 + y1i * c1);
  x[2] = make_float2(y2r * c2 - y2i * s2, y2r * s2 + y2i * c2);
  x[3] = make_float2(y3r * c3 - y3i * s3, y3r * s3 + y3i * c3);
}

template <int S>
__device__ __forceinline__ void inv_stage(float2 x[4], int t) {
  float c1 = 1.0f, s1 = 0.0f;
  if (S > 1) {
    const int j = t & (S - 1);
    __sincosf(2.0f * PI_F * (float)j / (float)(4 * S), &s1, &c1);
  }
  const float c2 = c1 * c1 - s1 * s1, s2 = 2.0f * c1 * s1;
  const float c3 = c1 * c2 - s1 * s2, s3 = c1 * s2 + s1 * c2;
  const float u0r = x[0].x,                   u0i = x[0].y;
  const float u1r = x[1].x * c1 - x[1].y * s1, u1i = x[1].x * s1 + x[1].y * c1;
  const float u2r = x[2].x * c2 - x[2].y * s2, u2i = x[2].x * s2 + x[2].y * c2;
  const float u3r = x[3].x * c3 - x[3].y * s3, u3i = x[3].x * s3 + x[3].y * c3;
  const float Er = u0r + u2r, Ei = u0i + u2i;
  const float Fr = u0r - u2r, Fi = u0i - u2i;
  const float Gr = u1r + u3r, Gi = u1i + u3i;
  const float Hr = u1r - u3r, Hi = u1i - u3i;
  x[0] = make_float2(Er + Gr, Ei + Gi);
  x[1] = make_float2(Fr - Hi, Fi + Hr);
  x[2] = make_float2(Er - Gr, Ei - Gi);
  x[3] = make_float2(Fr + Hi, Fi - Hr);
}

__device__ __forceinline__ void xpose(float2 x[4][4]) {
  #pragma unroll
  for (int a = 0; a < 4; ++a)
    #pragma unroll
    for (int b = a + 1; b < 4; ++b) {
      const float2 tmp = x[a][b]; x[a][b] = x[b][a]; x[b][a] = tmp;
    }
}

template <int SW, int SR>
__device__ __forceinline__ void xchg_w(float2* wbuf, float2 x[4][4], int l) {
  constexpr int LW = clog2(SW), LR = clog2(SR);
  #pragma unroll
  for (int j = 0; j < 4; ++j) {
    const int t = l + 64 * j;
    #pragma unroll
    for (int n = 0; n < 4; ++n)
      wbuf[pidx(((t >> LW) << (LW + 2)) + (t & (SW - 1)) + n * SW)] = x[j][n];
  }
  DSFENCE;
  #pragma unroll
  for (int j = 0; j < 4; ++j) {
    const int t = l + 64 * j;
    #pragma unroll
    for (int n = 0; n < 4; ++n)
      x[j][n] = wbuf[pidx(((t >> LR) << (LR + 2)) + (t & (SR - 1)) + n * SR)];
  }
  DSFENCE;
}

// ends with full spectrum in wbuf at digit-reversed positions
__device__ __forceinline__ void fwd_fft_wave(float2* wbuf, float2 x[4][4], int l) {
  #pragma unroll
  for (int j = 0; j < 4; ++j) fwd_stage<256>(x[j], l + 64 * j);
  xpose(x);                                   // 256->64 exchange, in-register
  #pragma unroll
  for (int j = 0; j < 4; ++j) fwd_stage<64>(x[j], l + 64 * j);
  xchg_w<64, 16>(wbuf, x, l);
  #pragma unroll
  for (int j = 0; j < 4; ++j) fwd_stage<16>(x[j], l + 64 * j);
  xchg_w<16, 4>(wbuf, x, l);
  #pragma unroll
  for (int j = 0; j < 4; ++j) fwd_stage<4>(x[j], l + 64 * j);
  xchg_w<4, 1>(wbuf, x, l);
  #pragma unroll
  for (int j = 0; j < 4; ++j) fwd_stage<1>(x[j], l + 64 * j);
  #pragma unroll
  for (int j = 0; j < 4; ++j)
    #pragma unroll
    for (int n = 0; n < 4; ++n)
      wbuf[pidx(4 * (l + 64 * j) + n)] = x[j][n];
  DSFENCE;
}

// ---------------------------------------------------------------------------
// Bind: 4 rows/block (one per wave), in place. KV row = element-interleaved
// (k,v) bf16 pairs -> one FFT of k+iv -> Hermitian split -> P packed to half
// spectrum over the same 4 KB (slot 0 = (P[0],P[512]), slot s = P[s]).
// ---------------------------------------------------------------------------
__global__ __launch_bounds__(256) void bind_kernel(unsigned short* __restrict__ KV) {
  __shared__ float2 sbuf[4][BUFSZ];
  const int l = threadIdx.x & 63;
  const int w = threadIdx.x >> 6;
  float2* wbuf = sbuf[w];
  unsigned short* rp = KV + ((long)blockIdx.x * 4 + w) * 2048;
  const unsigned int* rp32 = (const unsigned int*)rp;

  float2 x[4][4];
  #pragma unroll
  for (int j = 0; j < 4; ++j)
    #pragma unroll
    for (int n = 0; n < 4; ++n) {
      const unsigned int u = rp32[l + 64 * j + 256 * n];
      x[j][n] = make_float2(bf2f((unsigned short)(u & 0xffffu)),
                            bf2f((unsigned short)(u >> 16)));   // k + i*v
    }
  fwd_fft_wave(wbuf, x, l);

  float2* Prow = (float2*)rp;   // all row reads done (inputs fully in regs)
  #pragma unroll
  for (int u = 0; u < 8; ++u) {
    const int s = l + 64 * u;              // 0..511
    if (s == 0) {
      const float2 W0   = wbuf[pidx(0)];   // bin 0
      const float2 W512 = wbuf[pidx(2)];   // bin 512 (rev4(512)=2)
      Prow[0] = make_float2(W0.x * W0.y, W512.x * W512.y);
    } else {
      const int p1 = rev4(s);
      const int p2 = rev4(1024 - s);
      const float2 F1 = wbuf[pidx(p1)], F2 = wbuf[pidx(p2)];
      const float fkr = 0.5f * (F1.x + F2.x), fki = 0.5f * (F1.y - F2.y);
      const float fvr = 0.5f * (F1.y + F2.y), fvi = 0.5f * (F2.x - F1.x);
      Prow[s] = make_float2(fkr * fvr - fki * fvi, fkr * fvi + fki * fvr);
    }
  }
}

// ---------------------------------------------------------------------------
// Scan kernels (unchanged, known-good).
// ---------------------------------------------------------------------------
__global__ __launch_bounds__(256) void scan_chunk_sum(
    const float2* __restrict__ P, float2* __restrict__ csum) {
  const int chunk = blockIdx.x;
  const int batch = blockIdx.y >> 1;
  const int f = (blockIdx.y & 1) * 256 + threadIdx.x;
  long base = ((long)batch * SS + (long)chunk * RR) * 512 + f;
  float sr = 0.0f, si = 0.0f;
  #pragma unroll 4
  for (int i = 0; i < RR; ++i) {
    float2 p = P[base + (long)i * 512];
    sr += p.x; si += p.y;
  }
  csum[((long)batch * CH + chunk) * 512 + f] = make_float2(sr, si);
}

__global__ __launch_bounds__(256) void scan_chunk_scan(float2* csum) {
  const int idx = blockIdx.x * 256 + threadIdx.x;
  const int batch = idx >> 9;
  const int f = idx & 511;
  float2 v[CH];
  #pragma unroll
  for (int c = 0; c < CH; ++c) v[c] = csum[((long)batch * CH + c) * 512 + f];
  float rr = 0.0f, ri = 0.0f;
  #pragma unroll
  for (int c = 0; c < CH; ++c) {
    const float2 x = v[c];
    csum[((long)batch * CH + c) * 512 + f] = make_float2(rr, ri);
    rr += x.x; ri += x.y;
  }
}

__global__ __launch_bounds__(256) void scan_apply(
    float2* __restrict__ P, const float2* __restrict__ csum) {
  const int chunk = blockIdx.x;
  const int batch = blockIdx.y >> 1;
  const int f = (blockIdx.y & 1) * 256 + threadIdx.x;
  float2 off = csum[((long)batch * CH + chunk) * 512 + f];
  float ar = off.x, ai = off.y;
  long base = ((long)batch * SS + (long)chunk * RR) * 512 + f;
  for (int i = 0; i < RR; ++i) {
    const long o = base + (long)i * 512;
    float2 p = P[o];
    ar += p.x; ai += p.y;
    P[o] = make_float2(ar, ai);
  }
}

// ---------------------------------------------------------------------------
// Unbind: 8 rows/block (2 per wave), in place on d_out. One fwd FFT of
// q0+i*q1; mem gathered directly from global (Hermitian-packed rows are 4 KB,
// L1-resident) with predicated conj/unpack; one inv FFT of z0+i*z1.
// ---------------------------------------------------------------------------
__global__ __launch_bounds__(256) void unbind_kernel(
    float* __restrict__ qout, const float2* __restrict__ mem) {
  __shared__ float2 sbuf[4][BUFSZ];
  const int l = threadIdx.x & 63;
  const int w = threadIdx.x >> 6;
  float2* wbuf = sbuf[w];
  const long r0 = ((long)blockIdx.x * 4 + w) * 2;
  float* row0 = qout + r0 * DD;
  float* row1 = row0 + DD;
  const float2* mem0 = mem + r0 * 512;
  const float2* mem1 = mem0 + 512;

  float2 x[4][4];
  #pragma unroll
  for (int j = 0; j < 4; ++j)
    #pragma unroll
    for (int n = 0; n < 4; ++n) {
      const int i = l + 64 * j + 256 * n;
      x[j][n] = make_float2(row0[i], row1[i]);   // q0 + i*q1
    }
  fwd_fft_wave(wbuf, x, l);

  float2 z[4][4];
  #pragma unroll
  for (int j = 0; j < 4; ++j)
    #pragma unroll
    for (int m = 0; m < 4; ++m) {
      const int p   = l + 64 * j + 256 * m;
      const int bin = rev4(p);
      const int p2  = rev4((1024 - bin) & 1023);
      const float2 F1 = wbuf[pidx(p)], F2 = wbuf[pidx(p2)];
      const float q0r = 0.5f * (F1.x + F2.x), q0i = 0.5f * (F1.y - F2.y);
      const float q1r = 0.5f * (F1.y + F2.y), q1i = 0.5f * (F2.x - F1.x);
      float2 m0, m1;
      if (bin == 0 || bin == 512) {        // packed real pair in slot 0
        const float2 a = mem0[0], b = mem1[0];
        m0 = make_float2(bin ? a.y : a.x, 0.0f);
        m1 = make_float2(bin ? b.y : b.x, 0.0f);
      } else {
        const int  ix = (bin < 512) ? bin : 1024 - bin;
        const float sg = (bin < 512) ? 1.0f : -1.0f;
        m0 = mem0[ix]; m1 = mem1[ix];
        m0.y *= sg; m1.y *= sg;
      }
      const float z0r = m0.x * q0r + m0.y * q0i, z0i = m0.y * q0r - m0.x * q0i;
      const float z1r = m1.x * q1r + m1.y * q1i, z1i = m1.y * q1r - m1.x * q1i;
      z[j][m] = make_float2(z0r - z1i, z0i + z1r);   // z0 + i*z1
    }
  DSFENCE;   // all wbuf reads issued before the overwrite below (in-wave order)
  #pragma unroll
  for (int j = 0; j < 4; ++j)
    #pragma unroll
    for (int m = 0; m < 4; ++m)
      wbuf[pidx(l + 64 * j + 256 * m)] = z[j][m];
  DSFENCE;
  #pragma unroll
  for (int j = 0; j < 4; ++j)
    #pragma unroll
    for (int n = 0; n < 4; ++n)
      x[j][n] = wbuf[pidx(4 * (l + 64 * j) + n)];
  DSFENCE;

  #pragma unroll
  for (int j = 0; j < 4; ++j) inv_stage<1>(x[j], l + 64 * j);
  xchg_w<1, 4>(wbuf, x, l);
  #pragma unroll
  for (int j = 0; j < 4; ++j) inv_stage<4>(x[j], l + 64 * j);
  xchg_w<4, 16>(wbuf, x, l);
  #pragma unroll
  for (int j = 0; j < 4; ++j) inv_stage<16>(x[j], l + 64 * j);
  xchg_w<16, 64>(wbuf, x, l);
  #pragma unroll
  for (int j = 0; j < 4; ++j) inv_stage<64>(x[j], l + 64 * j);
  xpose(x);                                  // 64->256 exchange, in-register
  #pragma unroll
  for (int j = 0; j < 4; ++j) inv_stage<256>(x[j], l + 64 * j);

  const float sc = 1.0f / 1024.0f;
  #pragma unroll
  for (int j = 0; j < 4; ++j)
    #pragma unroll
    for (int n = 0; n < 4; ++n) {
      const int i = l + 64 * j + 256 * n;
      row0[i] = x[j][n].x * sc;
      row1[i] = x[j][n].y * sc;
    }
}

// ---------------------------------------------------------------------------
extern "C" void kernel_launch(void* const* d_in, const int* in_sizes, int n_in,
                              void* d_out, int out_size, void* d_ws, size_t ws_size,
                              hipStream_t stream) {
  (void)in_sizes; (void)n_in; (void)out_size;
  const float* x  = (const float*)d_in[0];
  const float* Wq = (const float*)d_in[1];
  const float* Wk = (const float*)d_in[2];
  const float* Wv = (const float*)d_in[3];
  float* out = (float*)d_out;

  // ws layout: Wb 6.29 MB | xb MH*2 KB | KV/P MH*4 KB | csum nB*0.26 MB
  // Single-pass (MH=8192): 57.67 MB (proven-safe: R7 ran it). Fallback: 2-pass.
  const size_t wbytes = (size_t)3 * DD * DD * 2;
  auto need = [&](size_t MHr, size_t nB) {
    return wbytes + MHr * DD * 2 + MHr * 4096 + nB * CH * 512 * 8;
  };
  const int nPass = (ws_size >= need(8192, 4)) ? 1 : 2;
  const size_t MH = MM / nPass;
  const int    nB = BB / nPass;

  char* ws = (char*)d_ws;
  unsigned short* Wb = (unsigned short*)ws;
  unsigned short* xb = (unsigned short*)(ws + wbytes);
  unsigned short* KV = (unsigned short*)(ws + wbytes + MH * DD * 2);
  float2*       csum = (float2*)((char*)KV + MH * 4096);

  const int nx = (int)(MH * DD / 1024);
  for (int h = 0; h < nPass; ++h) {
    const float* xh   = x   + (size_t)h * MH * DD;
    float*       outh = out + (size_t)h * MH * DD;

    // h=0 also converts the 3 weight matrices (extra 3072 blocks)
    convert_all<<<nx + (h == 0 ? 3072 : 0), 256, 0, stream>>>(
        xh, Wq, Wk, Wv, xb, Wb, nx);
    gemm_mfma<<<dim3(MH / 128, DD / 128, 3), 256, 0, stream>>>(xb, Wb, outh, KV);
    bind_kernel<<<MH / 4, 256, 0, stream>>>(KV);
    scan_chunk_sum<<<dim3(CH, nB * 2), 256, 0, stream>>>((const float2*)KV, csum);
    scan_chunk_scan<<<nB * 2, 256, 0, stream>>>(csum);
    scan_apply<<<dim3(CH, nB * 2), 256, 0, stream>>>((float2*)KV, csum);
    unbind_kernel<<<MH / 8, 256, 0, stream>>>(outh, (const float2*)KV);
  }
}